// Round 9
// baseline (147.673 us; speedup 1.0000x reference)
//
#include <hip/hip_runtime.h>
#include <stdint.h>
#include <stddef.h>

typedef __bf16 bf16_t;
typedef __bf16 bf16x8 __attribute__((ext_vector_type(8)));
typedef __bf16 bf16x4 __attribute__((ext_vector_type(4)));
typedef float f32x4 __attribute__((ext_vector_type(4)));

#define VMW(n) asm volatile("s_waitcnt vmcnt(" #n ")" ::: "memory")
#define LGKM0 asm volatile("s_waitcnt lgkmcnt(0)" ::: "memory")
#define CFENCE asm volatile("" ::: "memory")
#define RAWBAR              \
  do {                      \
    __builtin_amdgcn_s_barrier(); \
    CFENCE;                 \
  } while (0)

__device__ __forceinline__ void gload_lds16(const void* g, void* l) {
  __builtin_amdgcn_global_load_lds(
      (const __attribute__((address_space(1))) uint32_t*)g,
      (__attribute__((address_space(3))) uint32_t*)l, 16, 0, 0);
}

// ---------------- w2s: w2s[r*256+m] = sum_n w2[((r*256+m)*64)+n] ----------------
__global__ __launch_bounds__(256) void w2s_k(const float* __restrict__ w2,
                                             float* __restrict__ w2s) {
  const int r = blockIdx.x, m = threadIdx.x;
  const float4* p = (const float4*)(w2 + ((size_t)(r * 256 + m)) * 64);
  float s = 0.f;
#pragma unroll
  for (int i = 0; i < 16; ++i) {
    float4 v = p[i];
    s += (v.x + v.y) + (v.z + v.w);
  }
  w2s[r * 256 + m] = s;
}

// ---------------- merged prep ----------------
// blocks 0..255:   w1t[m*4096+k] = bf16(w1[k*256+m] * w2s[(k&63)*256+m])
// blocks 256..511: w3pt[(o*64+r)*256+m] = bf16(w3[m*4096 + r*64 + o])
// block 512:       c2[m] = sum_r bias1[r]*w2s[r*256+m] + 64*bias2[m]
__global__ __launch_bounds__(256) void prep_k(
    const float* __restrict__ w1, const float* __restrict__ w3,
    const float* __restrict__ w2s, const float* __restrict__ bias1,
    const float* __restrict__ bias2, bf16_t* __restrict__ w1t,
    bf16_t* __restrict__ w3pt, float* __restrict__ c2) {
  __shared__ float lds[64][65];
  const int b = blockIdx.x;
  const int t = threadIdx.x;
  if (b == 512) {
    float s = 64.f * bias2[t];
#pragma unroll 8
    for (int r = 0; r < 64; ++r) s += bias1[r] * w2s[r * 256 + t];
    c2[t] = s;
    return;
  }
  if (b < 256) {
    const int k0 = (b >> 2) * 64;
    const int mt = (b & 3) * 64;
#pragma unroll
    for (int it = 0; it < 16; ++it) {
      int idx = t + it * 256;
      int kl = idx >> 6, ml = idx & 63;
      int k = k0 + kl;
      lds[kl][ml] = w1[(size_t)k * 256 + mt + ml] * w2s[(k & 63) * 256 + mt + ml];
    }
    __syncthreads();
#pragma unroll
    for (int it = 0; it < 16; ++it) {
      int idx = t + it * 256;
      int ml = idx >> 6, kl = idx & 63;
      w1t[(size_t)(mt + ml) * 4096 + k0 + kl] = (bf16_t)lds[kl][ml];
    }
    return;
  }
  const int b2 = b - 256;
  const int r = b2 & 63;
  const int mt = (b2 >> 6) * 64;
#pragma unroll
  for (int it = 0; it < 16; ++it) {
    int idx = t + it * 256;
    int ml = idx >> 6, o = idx & 63;
    lds[ml][o] = w3[(size_t)(mt + ml) * 4096 + r * 64 + o];
  }
  __syncthreads();
#pragma unroll
  for (int it = 0; it < 16; ++it) {
    int idx = t + it * 256;
    int o = idx >> 6, ml = idx & 63;
    w3pt[(size_t)(o * 64 + r) * 256 + mt + ml] = (bf16_t)lds[ml][o];
  }
}

// ---------------- GEMM1: barrier-free, LDS-free (except wave-private epilogue) ----
// S4[t, ks*256+n] = sum_{k in slice ks (512 wide)} bf16(X[t,k]) * W1T[n,k]
// 512 blocks x 256 thr = 2048 independent waves; wave w: rows (w>>3)*32..+31, ks=w&7
// per wave: 16 steps of BK=32; A direct from X (fp32->bf16 in reg), B direct from
// W1T (L2/L3-resident, 2MB); 32 MFMA/step; NO __syncthreads anywhere.
__global__ __launch_bounds__(256, 2) void gemm1_k(
    const float* __restrict__ X, const bf16_t* __restrict__ W1T,
    bf16_t* __restrict__ S4) {
  __shared__ __align__(16) bf16_t eps[4][32 * 256];  // wave-private epilogue buffers
  const int tid = threadIdx.x;
  const int lane = tid & 63;
  const int wv = tid >> 6;
  const int w = (int)blockIdx.x * 4 + wv;  // 0..2047
  const int rowgrp = w >> 3;               // 0..255
  const int ks = w & 7;                    // k-slice
  const size_t m0 = (size_t)rowgrp * 32;
  const int kbase = ks * 512;
  const int lr = lane & 15;                // fragment row index (m or n)
  const int lk = (lane >> 4) * 8;          // fragment k-offset (elements)

  f32x4 acc[2][16];
#pragma unroll
  for (int i = 0; i < 2; ++i)
#pragma unroll
    for (int j = 0; j < 16; ++j) acc[i][j] = (f32x4){0.f, 0.f, 0.f, 0.f};

  const float* xb0 = X + (m0 + lr) * 4096 + (size_t)(kbase + lk);
  const float* xb1 = X + (m0 + 16 + lr) * 4096 + (size_t)(kbase + lk);
  const bf16_t* bb = W1T + (size_t)lr * 4096 + (size_t)(kbase + lk);

#pragma unroll 2
  for (int kt = 0; kt < 16; ++kt) {
    const int ko = kt * 32;
    // A fragments: 32 rows x 32 k fp32 -> bf16
    float4 u0 = *(const float4*)(xb0 + ko);
    float4 v0 = *(const float4*)(xb0 + ko + 4);
    float4 u1 = *(const float4*)(xb1 + ko);
    float4 v1 = *(const float4*)(xb1 + ko + 4);
    bf16x8 a0, a1;
    a0[0] = (bf16_t)u0.x; a0[1] = (bf16_t)u0.y; a0[2] = (bf16_t)u0.z; a0[3] = (bf16_t)u0.w;
    a0[4] = (bf16_t)v0.x; a0[5] = (bf16_t)v0.y; a0[6] = (bf16_t)v0.z; a0[7] = (bf16_t)v0.w;
    a1[0] = (bf16_t)u1.x; a1[1] = (bf16_t)u1.y; a1[2] = (bf16_t)u1.z; a1[3] = (bf16_t)u1.w;
    a1[4] = (bf16_t)v1.x; a1[5] = (bf16_t)v1.y; a1[6] = (bf16_t)v1.z; a1[7] = (bf16_t)v1.w;
    // B fragments in groups of 4 (caps register liveness)
#pragma unroll
    for (int g = 0; g < 4; ++g) {
      bf16x8 b0 = *(const bf16x8*)(bb + (size_t)(g * 4 + 0) * 16 * 4096 + ko);
      bf16x8 b1 = *(const bf16x8*)(bb + (size_t)(g * 4 + 1) * 16 * 4096 + ko);
      bf16x8 b2 = *(const bf16x8*)(bb + (size_t)(g * 4 + 2) * 16 * 4096 + ko);
      bf16x8 b3 = *(const bf16x8*)(bb + (size_t)(g * 4 + 3) * 16 * 4096 + ko);
      acc[0][g * 4 + 0] = __builtin_amdgcn_mfma_f32_16x16x32_bf16(a0, b0, acc[0][g * 4 + 0], 0, 0, 0);
      acc[1][g * 4 + 0] = __builtin_amdgcn_mfma_f32_16x16x32_bf16(a1, b0, acc[1][g * 4 + 0], 0, 0, 0);
      acc[0][g * 4 + 1] = __builtin_amdgcn_mfma_f32_16x16x32_bf16(a0, b1, acc[0][g * 4 + 1], 0, 0, 0);
      acc[1][g * 4 + 1] = __builtin_amdgcn_mfma_f32_16x16x32_bf16(a1, b1, acc[1][g * 4 + 1], 0, 0, 0);
      acc[0][g * 4 + 2] = __builtin_amdgcn_mfma_f32_16x16x32_bf16(a0, b2, acc[0][g * 4 + 2], 0, 0, 0);
      acc[1][g * 4 + 2] = __builtin_amdgcn_mfma_f32_16x16x32_bf16(a1, b2, acc[1][g * 4 + 2], 0, 0, 0);
      acc[0][g * 4 + 3] = __builtin_amdgcn_mfma_f32_16x16x32_bf16(a0, b3, acc[0][g * 4 + 3], 0, 0, 0);
      acc[1][g * 4 + 3] = __builtin_amdgcn_mfma_f32_16x16x32_bf16(a1, b3, acc[1][g * 4 + 3], 0, 0, 0);
    }
  }

  // epilogue: wave-private LDS transpose -> coalesced bf16x8 global stores
  bf16_t* ep = &eps[wv][0];
#pragma unroll
  for (int mf = 0; mf < 2; ++mf)
#pragma unroll
    for (int nf = 0; nf < 16; ++nf)
#pragma unroll
      for (int q = 0; q < 4; ++q) {
        int row = mf * 16 + (lane >> 4) * 4 + q;
        int col = nf * 16 + lr;
        ep[row * 256 + col] = (bf16_t)acc[mf][nf][q];
      }
  LGKM0;  // wave-private: ds_writes complete before reads, no barrier needed
  __builtin_amdgcn_sched_barrier(0);
#pragma unroll
  for (int it = 0; it < 16; ++it) {
    int chunk = it * 64 + lane;  // 0..1023 chunks of 8 bf16
    int row = chunk >> 5;        // 0..31
    int c8 = (chunk & 31) << 3;
    bf16x8 v = *(const bf16x8*)(ep + row * 256 + c8);
    *(bf16x8*)(S4 + (m0 + row) * 2048 + (size_t)(ks * 256 + c8)) = v;
  }
}

// ---------------- reduce: S[t,m] = bf16( sum_{h=0..7} S4[t, h*256+m] + c2[m] )
__global__ __launch_bounds__(256) void reduce_k(
    const bf16_t* __restrict__ S4, const float* __restrict__ c2,
    bf16_t* __restrict__ S) {
  const int gid = (int)blockIdx.x * 256 + threadIdx.x;
  const int row = gid >> 5;
  const int c8 = (gid & 31) << 3;
  float s[8];
  float4 ca = *(const float4*)(c2 + c8);
  float4 cb = *(const float4*)(c2 + c8 + 4);
  s[0] = ca.x; s[1] = ca.y; s[2] = ca.z; s[3] = ca.w;
  s[4] = cb.x; s[5] = cb.y; s[6] = cb.z; s[7] = cb.w;
#pragma unroll
  for (int h = 0; h < 8; ++h) {
    bf16x8 v = *(const bf16x8*)(S4 + (size_t)row * 2048 + h * 256 + c8);
#pragma unroll
    for (int j = 0; j < 8; ++j) s[j] += (float)v[j];
  }
  bf16x8 o;
#pragma unroll
  for (int j = 0; j < 8; ++j) o[j] = (bf16_t)s[j];
  *(bf16x8*)(S + (size_t)row * 256 + c8) = o;
}

// ---------------- GEMM2: OUT[t, j] = sum_{m=0..255} S[t,m] * W3pT[j, m] + bias3[j&63]
// grid 1024 = 8 xcd x 8 mt x 16 nt; 512 threads = 8 waves (2M x 4N), wave tile 64x64
// BM=128, BN=256, BK=64, NT=4; both operands via global_load_lds; counted vmcnt
__global__ __launch_bounds__(512, 2) void gemm2_k(
    const bf16_t* __restrict__ S, const bf16_t* __restrict__ W3pT,
    const float* __restrict__ bias3, float* __restrict__ OUT) {
  __shared__ __align__(16) bf16_t lA[2][128 * 64];
  __shared__ __align__(16) bf16_t lB[2][256 * 64];
  const int tid = threadIdx.x;
  const int lane = tid & 63;
  const int wv = tid >> 6;
  const int bid = (int)blockIdx.x;
  const int xcd = bid & 7;
  const int rest = bid >> 3;            // 0..127
  const int mt = xcd * 8 + (rest >> 4);
  const int nt = rest & 15;
  const size_t m0 = (size_t)mt * 128;
  const int n0 = nt * 256;
  const int wm = wv >> 2, wn = wv & 3;

  f32x4 acc[4][4];
#pragma unroll
  for (int i = 0; i < 4; ++i)
#pragma unroll
    for (int j = 0; j < 4; ++j) acc[i][j] = (f32x4){0.f, 0.f, 0.f, 0.f};

  auto stage = [&](int buf, int kt) {
#pragma unroll
    for (int i = 0; i < 2; ++i) {
      int row = wv * 16 + i * 8 + (lane >> 3);
      int srckb = ((lane & 7) * 16) ^ ((row & 7) << 4);
      const char* srcA = (const char*)S + (m0 + row) * 512 + (size_t)(kt * 128) + srckb;
      char* dstA = (char*)(&lA[buf][0]) + (wv * 16 + i * 8) * 128;
      gload_lds16(srcA, dstA);
    }
#pragma unroll
    for (int i = 0; i < 4; ++i) {
      int row = wv * 32 + i * 8 + (lane >> 3);
      int srckb = ((lane & 7) * 16) ^ ((row & 7) << 4);
      const char* srcB = (const char*)W3pT + (size_t)(n0 + row) * 512 + (size_t)(kt * 128) + srckb;
      char* dstB = (char*)(&lB[buf][0]) + (wv * 32 + i * 8) * 128;
      gload_lds16(srcB, dstB);
    }
  };
  auto compute = [&](int buf) {
#pragma unroll
    for (int kk = 0; kk < 2; ++kk) {
      const int kb = kk * 64 + ((lane >> 4) * 16);
      bf16x8 af[4], bfr[4];
#pragma unroll
      for (int mf = 0; mf < 4; ++mf) {
        int row = wm * 64 + mf * 16 + (lane & 15);
        int off = row * 128 + (kb ^ ((row & 7) << 4));
        af[mf] = *(const bf16x8*)((const char*)(&lA[buf][0]) + off);
      }
#pragma unroll
      for (int nf = 0; nf < 4; ++nf) {
        int row = wn * 64 + nf * 16 + (lane & 15);
        int off = row * 128 + (kb ^ ((row & 7) << 4));
        bfr[nf] = *(const bf16x8*)((const char*)(&lB[buf][0]) + off);
      }
#pragma unroll
      for (int mf = 0; mf < 4; ++mf)
#pragma unroll
        for (int nf = 0; nf < 4; ++nf)
          acc[mf][nf] = __builtin_amdgcn_mfma_f32_16x16x32_bf16(af[mf], bfr[nf], acc[mf][nf], 0, 0, 0);
    }
  };

  stage(0, 0);
  CFENCE;
  stage(1, 1);
  CFENCE;
  VMW(6);
  RAWBAR;
  compute(0);
  RAWBAR;
  stage(0, 2);
  CFENCE;
  VMW(6);
  RAWBAR;
  compute(1);
  RAWBAR;
  stage(1, 3);
  CFENCE;
  VMW(6);
  RAWBAR;
  compute(0);
  RAWBAR;
  VMW(0);
  RAWBAR;
  compute(1);

#pragma unroll
  for (int nf = 0; nf < 4; ++nf) {
    int jcol = wn * 64 + nf * 16 + (lane & 15);
    float b3 = bias3[jcol & 63];
    int j = n0 + jcol;
#pragma unroll
    for (int mf = 0; mf < 4; ++mf) {
#pragma unroll
      for (int q = 0; q < 4; ++q) {
        size_t row = m0 + (size_t)(wm * 64 + mf * 16 + (lane >> 4) * 4 + q);
        OUT[row * 4096 + j] = acc[mf][nf][q] + b3;
      }
    }
  }
}

extern "C" void kernel_launch(void* const* d_in, const int* in_sizes, int n_in,
                              void* d_out, int out_size, void* d_ws, size_t ws_size,
                              hipStream_t stream) {
  (void)in_sizes; (void)n_in; (void)out_size; (void)ws_size;
  const float* x  = (const float*)d_in[0];
  const float* w1 = (const float*)d_in[1];
  const float* w2 = (const float*)d_in[2];
  const float* w3 = (const float*)d_in[3];
  const float* b1 = (const float*)d_in[4];
  const float* b2 = (const float*)d_in[5];
  const float* b3 = (const float*)d_in[6];
  float* out = (float*)d_out;
  char* ws = (char*)d_ws;

  // workspace layout
  float*  w2s  = (float*)(ws + 0);                   // 64 KB
  float*  c2   = (float*)(ws + 65536);               // 1 KB (+pad)
  bf16_t* w1t  = (bf16_t*)(ws + 69632);              // 2 MB  [256][4096] bf16
  bf16_t* w3pt = (bf16_t*)(ws + 69632 + 2097152);    // 2 MB  [4096][256] bf16
  bf16_t* S4   = (bf16_t*)(ws + 69632 + 4194304);    // 32 MB [8192][2048] bf16
  bf16_t* S    = (bf16_t*)(ws + 69632 + 4194304 + 33554432);  // 4 MB [8192][256] bf16

  w2s_k<<<64, 256, 0, stream>>>(w2, w2s);
  prep_k<<<513, 256, 0, stream>>>(w1, w3, w2s, b1, b2, w1t, w3pt, c2);
  gemm1_k<<<512, 256, 0, stream>>>(x, w1t, S4);
  reduce_k<<<1024, 256, 0, stream>>>(S4, c2, S);
  gemm2_k<<<1024, 512, 0, stream>>>(S, w3pt, b3, out);
}